// Round 1
// baseline (407.268 us; speedup 1.0000x reference)
//
#include <hip/hip_runtime.h>

// VectorQuantizer: x (32,64,64,64) f32, codebook (1024,64) f32
// out = concat( quantized (32,64,64,64) f32 , indices (32,64,64) as f32 )
//
// R7: single-pass f16 main distance + packed (dist|code) float keys + LDS
// double-buffered codebook + 16 waves/CU.
//  - R6 post-mortem: 99 us with MfmaUtil 21 / VALU 27 / Occ 21.7 -> latency
//    bound at 2 waves/SIMD on the global B stream. Fix all three:
//  - 6 MFMA/tile split-precision -> 2 MFMA/tile plain f16. Worst-case dist
//    error 2*2u*||x||*||e|| + key-trunc <= ~0.6; EPS widened 2e-3 -> 1.0.
//    Flagged (~10-15%) positions get the exact-f32 rescan (verified path).
//  - key = (float_bits(dist) & ~1023) | code: top-2 via fmed3f+fminf only
//    (3 VALU/pair), tie->min-code automatic, margin slop absorbed by EPS.
//  - codebook f16 stream (128 KB) staged via LDS, 8 x 16 KB chunks,
//    double-buffered, reg-staged, ONE __syncthreads per chunk (prefetch
//    distance = full 8-ct compute phase >> L2 latency).
//  - wave = 32 positions (2 M-tiles), grid 1024, __launch_bounds__(256,4)
//    -> 4 blocks/CU (37.9 KB LDS each) = 16 waves/CU.

typedef _Float16 f16x8 __attribute__((ext_vector_type(8)));
typedef float    f32x4 __attribute__((ext_vector_type(4)));

#define VQ_D    64
#define VQ_HW   4096
#define VQ_NPOS 131072
#define EPS     1.0f
#define WS_CBN  65536      // f32 cn[1024]           (bp = 8192 f16x8 = 128 KB before it)
#define WS_CBT  66560      // float4 cbT4[16384]     (256 KB)
#define WS_CNT  132096     // int rescan counter
#define WS_LIST 132100     // int list[131072]

// ---------- prep ----------
// bp item: it=(ct*2+s)*64+lane; s = ks (K-half). value = -2*f16(b) (exact).
__global__ __launch_bounds__(256)
void vq_prep(const float* __restrict__ cb, float* __restrict__ ws)
{
    const int tid = threadIdx.x;
    const int blk = blockIdx.x;
    if (blk < 32) {
        const int it   = blk * 256 + tid;            // [0, 8192)
        const int ct   = it >> 7;
        const int s    = (it >> 6) & 1;
        const int lane = it & 63;
        const int n    = ct * 16 + (lane & 15);      // code (B column)
        const int k0   = s * 32 + (lane >> 4) * 8;   // dim  (B row)
        const float* src = cb + n * 64 + k0;
        f16x8 o;
        #pragma unroll
        for (int j = 0; j < 8; ++j)
            o[j] = (_Float16)(-2.0f * (float)(_Float16)src[j]);
        ((f16x8*)ws)[it] = o;
    } else if (blk < 96) {
        const int it = (blk - 32) * 256 + tid;       // [0, 16384)
        const int k = it >> 4, j4 = it & 15;
        ((float4*)(ws + WS_CBT))[j4 * 1024 + k] = ((const float4*)cb)[it];
    } else {
        const int k = (blk - 96) * 256 + tid;        // [0, 1024)
        const float4* row = (const float4*)(cb + k * 64);
        float a0 = 0.f, a1 = 0.f, a2 = 0.f, a3 = 0.f;
        #pragma unroll
        for (int j = 0; j < 16; ++j) {
            const float4 c = row[j];
            a0 = fmaf(c.x, c.x, a0); a1 = fmaf(c.y, c.y, a1);
            a2 = fmaf(c.z, c.z, a2); a3 = fmaf(c.w, c.w, a3);
        }
        ws[WS_CBN + k] = (a0 + a1) + (a2 + a3);
        if (k == 0) ((int*)ws)[WS_CNT] = 0;
    }
}

// ---------- main ----------
__global__ __launch_bounds__(256, 4)
void vq_main(const float* __restrict__ x,
             const float* __restrict__ cb,
             float* __restrict__ ws,
             float* __restrict__ out,
             float* __restrict__ idx_out)
{
    __shared__ f16x8 bbuf[2][1024];   // 2 x 16 KB codebook chunk (8 ct each)
    __shared__ float cn_lds[1024];    // 4 KB ||e||^2
    __shared__ int   sk[128];
    __shared__ float smg[128];

    const int tid  = threadIdx.x;
    const int lane = tid & 63;
    const int wv   = tid >> 6;        // 4 waves
    const int m    = lane & 15;
    const int q    = lane >> 4;

    const int p0 = blockIdx.x * 128;  // block: 128 consecutive positions
    const int b  = p0 >> 12;
    const int n0 = p0 & (VQ_HW - 1);
    const float* xw = x + (size_t)b * (VQ_D * VQ_HW) + n0 + wv * 32;

    // cn -> LDS (raw, identical values to rescan's global cn)
    ((float4*)cn_lds)[tid] = ((const float4*)(ws + WS_CBN))[tid];

    // issue chunk-0 loads (latency hidden under A-fragment build)
    const float4* g0 = (const float4*)ws;
    float4 u0 = g0[tid], u1 = g0[256 + tid], u2 = g0[512 + tid], u3 = g0[768 + tid];

    // ---- A fragments: f16(x), 2 M-tiles, resident ----
    f16x8 Ah[2][2];
    #pragma unroll
    for (int tl = 0; tl < 2; ++tl)
        #pragma unroll
        for (int ks = 0; ks < 2; ++ks) {
            f16x8 h8;
            #pragma unroll
            for (int j = 0; j < 8; ++j)
                h8[j] = (_Float16)xw[(size_t)(ks * 32 + q * 8 + j) * VQ_HW + tl * 16 + m];
            Ah[tl][ks] = h8;
        }

    {   // chunk 0 -> LDS
        float4* l0 = (float4*)(&bbuf[0][0]);
        l0[tid] = u0; l0[256 + tid] = u1; l0[512 + tid] = u2; l0[768 + tid] = u3;
    }

    float d1[2][4], d2[2][4];
    #pragma unroll
    for (int tl = 0; tl < 2; ++tl)
        #pragma unroll
        for (int r = 0; r < 4; ++r) { d1[tl][r] = 3.4e38f; d2[tl][r] = 3.4e38f; }

    for (int cc = 0; cc < 8; ++cc) {
        // top barrier: chunk cc visible to all waves; bbuf[(cc+1)&1] free
        __syncthreads();
        float4 t0, t1, t2, t3;
        if (cc < 7) {   // issue next-chunk loads now; consumed only at loop end
            const float4* g = (const float4*)((const char*)ws + (size_t)(cc + 1) * 16384);
            t0 = g[tid]; t1 = g[256 + tid]; t2 = g[512 + tid]; t3 = g[768 + tid];
        }
        const f16x8* bufc = &bbuf[cc & 1][0];
        #pragma unroll
        for (int ct = 0; ct < 8; ++ct) {
            const int ctg = cc * 8 + ct;
            const f16x8 B0 = bufc[ct * 128 + lane];
            const f16x8 B1 = bufc[ct * 128 + 64 + lane];
            const float cv = cn_lds[ctg * 16 + m];
            const f32x4 Ci = {cv, cv, cv, cv};
            f32x4 a0 = __builtin_amdgcn_mfma_f32_16x16x32_f16(Ah[0][0], B0, Ci, 0, 0, 0);
            a0       = __builtin_amdgcn_mfma_f32_16x16x32_f16(Ah[0][1], B1, a0, 0, 0, 0);
            f32x4 a1 = __builtin_amdgcn_mfma_f32_16x16x32_f16(Ah[1][0], B0, Ci, 0, 0, 0);
            a1       = __builtin_amdgcn_mfma_f32_16x16x32_f16(Ah[1][1], B1, a1, 0, 0, 0);
            const int code_ = ctg * 16 + m;
            #pragma unroll
            for (int r = 0; r < 4; ++r) {
                const float kf0 = __int_as_float((int)((__float_as_int(a0[r]) & 0xFFFFFC00u) | (unsigned)code_));
                d2[0][r] = __builtin_amdgcn_fmed3f(kf0, d1[0][r], d2[0][r]);
                d1[0][r] = fminf(kf0, d1[0][r]);
                const float kf1 = __int_as_float((int)((__float_as_int(a1[r]) & 0xFFFFFC00u) | (unsigned)code_));
                d2[1][r] = __builtin_amdgcn_fmed3f(kf1, d1[1][r], d2[1][r]);
                d1[1][r] = fminf(kf1, d1[1][r]);
            }
        }
        if (cc < 7) {   // write next chunk (other buffer; its readers finished
            float4* l = (float4*)(&bbuf[(cc + 1) & 1][0]);   // before top barrier)
            l[tid] = t0; l[256 + tid] = t1; l[512 + tid] = t2; l[768 + tid] = t3;
        }
    }

    // ---- top-2 merge across the 16 code-columns (keys carry the code) ----
    #pragma unroll
    for (int off = 1; off < 16; off <<= 1)
        #pragma unroll
        for (int tl = 0; tl < 2; ++tl)
            #pragma unroll
            for (int r = 0; r < 4; ++r) {
                const float od1 = __shfl_xor(d1[tl][r], off, 64);
                const float od2 = __shfl_xor(d2[tl][r], off, 64);
                d2[tl][r] = fminf(fmaxf(d1[tl][r], od1), fminf(d2[tl][r], od2));
                d1[tl][r] = fminf(d1[tl][r], od1);
            }

    if (m == 0) {
        #pragma unroll
        for (int tl = 0; tl < 2; ++tl)
            #pragma unroll
            for (int r = 0; r < 4; ++r) {
                const int li = wv * 32 + tl * 16 + q * 4 + r;
                sk[li]  = __float_as_int(d1[tl][r]) & 1023;
                smg[li] = d2[tl][r] - d1[tl][r];
            }
    }
    __syncthreads();

    // ---- epilogue: indices, rescan flags, quantized scatter ----
    const int pos  = tid & 127;
    const int half = tid >> 7;        // 2 threads per position, 32 dims each
    const int bk   = sk[pos];
    if (half == 0) {
        idx_out[p0 + pos] = (float)bk;
        if (smg[pos] < EPS) {
            const int slot = atomicAdd((int*)ws + WS_CNT, 1);
            ((int*)ws)[WS_LIST + slot] = p0 + pos;
        }
    }
    const float4* cr = (const float4*)(cb + (size_t)bk * VQ_D) + half * 8;
    float* ob = out + (size_t)b * (VQ_D * VQ_HW) + (size_t)(half * 32) * VQ_HW + n0 + pos;
    #pragma unroll
    for (int d4 = 0; d4 < 8; ++d4) {
        const float4 v = cr[d4];
        ob[(size_t)(d4 * 4 + 0) * VQ_HW] = v.x;
        ob[(size_t)(d4 * 4 + 1) * VQ_HW] = v.y;
        ob[(size_t)(d4 * 4 + 2) * VQ_HW] = v.z;
        ob[(size_t)(d4 * 4 + 3) * VQ_HW] = v.w;
    }
}

// ---------- rescan: exact f32 argmin for flagged positions ----------
__global__ __launch_bounds__(64)
void vq_rescan(const float* __restrict__ x,
               const float* __restrict__ cb,
               const float* __restrict__ ws,
               float* __restrict__ out,
               float* __restrict__ idx_out)
{
    __shared__ float xs[VQ_D];
    const int lane = threadIdx.x;
    const int cnt  = ((const int*)ws)[WS_CNT];
    const int* list = (const int*)ws + WS_LIST;
    const float*  cnb  = ws + WS_CBN;
    const float4* cbT4 = (const float4*)(ws + WS_CBT);

    for (int i = blockIdx.x; i < cnt; i += gridDim.x) {
        const int p = list[i];
        const int b = p >> 12, n = p & (VQ_HW - 1);
        xs[lane] = x[(size_t)b * (VQ_D * VQ_HW) + (size_t)lane * VQ_HW + n];
        __syncthreads();
        float4 xr[16];
        #pragma unroll
        for (int j = 0; j < 16; ++j) xr[j] = ((const float4*)xs)[j];

        float bd = 3.4e38f; int bk = 0;
        #pragma unroll 4
        for (int t = 0; t < 16; ++t) {
            const int code = t * 64 + lane;           // per-lane ascending
            float a0 = 0.f, a1 = 0.f, a2 = 0.f, a3 = 0.f;
            #pragma unroll
            for (int j4 = 0; j4 < 16; ++j4) {
                const float4 c = cbT4[j4 * 1024 + code];   // coalesced
                a0 = fmaf(xr[j4].x, c.x, a0); a1 = fmaf(xr[j4].y, c.y, a1);
                a2 = fmaf(xr[j4].z, c.z, a2); a3 = fmaf(xr[j4].w, c.w, a3);
            }
            const float dist = fmaf(-2.0f, (a0 + a1) + (a2 + a3), cnb[code]);
            if (dist < bd) { bd = dist; bk = code; }
        }
        #pragma unroll
        for (int off = 1; off < 64; off <<= 1) {      // min dist, tie -> min k
            const float od = __shfl_xor(bd, off, 64);
            const int   ok = __shfl_xor(bk, off, 64);
            if (od < bd || (od == bd && ok < bk)) { bd = od; bk = ok; }
        }
        out[(size_t)b * (VQ_D * VQ_HW) + (size_t)lane * VQ_HW + n] = cb[(size_t)bk * VQ_D + lane];
        if (lane == 0) idx_out[p] = (float)bk;
        __syncthreads();
    }
}

extern "C" void kernel_launch(void* const* d_in, const int* in_sizes, int n_in,
                              void* d_out, int out_size, void* d_ws, size_t ws_size,
                              hipStream_t stream) {
    const float* x  = (const float*)d_in[0];
    const float* cb = (const float*)d_in[1];
    float* out = (float*)d_out;
    float* idx = out + (size_t)VQ_NPOS * VQ_D;   // 8,388,608 floats in
    float* ws  = (float*)d_ws;                    // ~1.05 MB used

    vq_prep  <<<dim3(100),  dim3(256), 0, stream>>>(cb, ws);
    vq_main  <<<dim3(1024), dim3(256), 0, stream>>>(x, cb, ws, out, idx);
    vq_rescan<<<dim3(4096), dim3(64),  0, stream>>>(x, cb, ws, out, idx);
}

// Round 2
// 159.710 us; speedup vs baseline: 2.5500x; 2.5500x over previous
//
#include <hip/hip_runtime.h>

// VectorQuantizer: x (32,64,64,64) f32, codebook (1024,64) f32
// out = concat( quantized (32,64,64,64) f32 , indices (32,64,64) as f32 )
//
// R8 = R6's verified exact split-precision math + R7's occupancy/LDS wins,
// reconciled through INTEGER packed keys.
//  - R7 post-mortem: EPS=1.0 (needed for 1-pass f16) flagged ~27k positions
//    (FETCH 109MB / 4KB-per-pos) -> rescan 315 us, latency-bound. The
//    exactness tax moved into the worst possible kernel. Revert to 6-MFMA
//    split scheme (error <= ~2e-3, R6-verified absmax 0) -> ~130 flags.
//  - float packed keys truncate up to 0.06 at |dist|~512 (incompatible with
//    4e-3 margin). Integer keys instead: q = dist*2048 = fmaf(acm,SC,acc)
//    (ONE op since SC=2048), key = (cvt_i32(q)<<10)|code. OR on clear low
//    bits == add -> monotone both signs, tie -> min code. Quant error
//    <=1 LSB (4.9e-4); EPS_Q=16 LSB covers split error + 2 LSB with 2x slack.
//  - B stream (256 KB) staged via __builtin_amdgcn_global_load_lds, 16 KB
//    (4-ct) chunks, double-buffered, one __syncthreads per chunk. No staging
//    VGPRs -> fits 128-VGPR cap for __launch_bounds__(256,4): 16 waves/CU.
//  - wave = 32 positions (2 M-tiles), grid 1024 = exactly 4 blocks/CU.

typedef _Float16 f16x8 __attribute__((ext_vector_type(8)));
typedef float    f32x4 __attribute__((ext_vector_type(4)));

#define VQ_D    64
#define VQ_HW   4096
#define VQ_NPOS 131072
#define SC      2048.0f
#define EPS_Q   16         // flag margin in q-units (16/2048 = 7.8e-3)
#define WS_CBN  65536      // f32 cn[1024]           (bp = 16384 f16x8 = 256 KB before it)
#define WS_CBT  66560      // float4 cbT4[16384]     (256 KB)
#define WS_CNT  132096     // int rescan counter
#define WS_LIST 132100     // int list[131072]

// ---------- prep (R6's, verified) ----------
// bp item: it=(ct*4+s)*64+lane; s: 0=bh2 ks0, 1=bh2 ks1, 2=rb2k ks0, 3=rb2k ks1
// bh2 = -2*f16(b) (exact), rb2k = f16(-2*SC*(b - bh)).
__global__ __launch_bounds__(256)
void vq_prep(const float* __restrict__ cb, float* __restrict__ ws)
{
    const int tid = threadIdx.x;
    const int blk = blockIdx.x;
    if (blk < 64) {
        const int it   = blk * 256 + tid;            // [0, 16384)
        const int ct   = it >> 8;
        const int s    = (it >> 6) & 3;
        const int lane = it & 63;
        const int ks   = s & 1, isR = s >> 1;
        const int n    = ct * 16 + (lane & 15);      // code (B column)
        const int k0   = ks * 32 + (lane >> 4) * 8;  // dim  (B row)
        const float* src = cb + n * 64 + k0;
        f16x8 o;
        #pragma unroll
        for (int j = 0; j < 8; ++j) {
            const float b = src[j];
            const _Float16 bh = (_Float16)b;
            o[j] = isR ? (_Float16)((b - (float)bh) * (-2.0f * SC))
                       : (_Float16)(-2.0f * (float)bh);
        }
        ((f16x8*)ws)[it] = o;
    } else if (blk < 128) {
        const int it = (blk - 64) * 256 + tid;       // [0, 16384)
        const int k = it >> 4, j4 = it & 15;
        ((float4*)(ws + WS_CBT))[j4 * 1024 + k] = ((const float4*)cb)[it];
    } else {
        const int k = (blk - 128) * 256 + tid;       // [0, 1024)
        const float4* row = (const float4*)(cb + k * 64);
        float a0 = 0.f, a1 = 0.f, a2 = 0.f, a3 = 0.f;
        #pragma unroll
        for (int j = 0; j < 16; ++j) {
            const float4 c = row[j];
            a0 = fmaf(c.x, c.x, a0); a1 = fmaf(c.y, c.y, a1);
            a2 = fmaf(c.z, c.z, a2); a3 = fmaf(c.w, c.w, a3);
        }
        ws[WS_CBN + k] = (a0 + a1) + (a2 + a3);
        if (k == 0) ((int*)ws)[WS_CNT] = 0;
    }
}

// ---------- main ----------
#define GLOAD_LDS(GP, LP)                                                     \
    __builtin_amdgcn_global_load_lds(                                         \
        (const __attribute__((address_space(1))) unsigned int*)(GP),          \
        (__attribute__((address_space(3))) unsigned int*)(LP), 16, 0, 0)

__global__ __launch_bounds__(256, 4)
void vq_main(const float* __restrict__ x,
             const float* __restrict__ cb,
             float* __restrict__ ws,
             float* __restrict__ out,
             float* __restrict__ idx_out)
{
    __shared__ f16x8 bbuf[2][1024];   // 2 x 16 KB = 4-ct chunk (bh2+rb2k)
    __shared__ float cn_lds[1024];    // ||e||^2
    __shared__ int   sk[128];
    __shared__ int   smg[128];

    const int tid  = threadIdx.x;
    const int lane = tid & 63;
    const int wv   = tid >> 6;        // 4 waves
    const int m    = lane & 15;
    const int q    = lane >> 4;

    const int p0 = blockIdx.x * 128;  // block: 128 consecutive positions
    const int b  = p0 >> 12;
    const int n0 = p0 & (VQ_HW - 1);
    const float* xw = x + (size_t)b * (VQ_D * VQ_HW) + n0 + wv * 32;

    // cn -> LDS (visible after first __syncthreads)
    ((float4*)cn_lds)[tid] = ((const float4*)(ws + WS_CBN))[tid];

    // stage chunk 0 (latency hidden under A-fragment build)
    {
        const char* gsrc = (const char*)ws + wv * 4096 + lane * 16;
        char*       ldst = (char*)&bbuf[0][0] + wv * 4096;
        GLOAD_LDS(gsrc, ldst);                GLOAD_LDS(gsrc + 1024, ldst + 1024);
        GLOAD_LDS(gsrc + 2048, ldst + 2048);  GLOAD_LDS(gsrc + 3072, ldst + 3072);
    }

    // ---- A fragments (hi + scaled residual), 2 M-tiles, resident ----
    f16x8 Ah[2][2], Ra[2][2];
    #pragma unroll
    for (int tl = 0; tl < 2; ++tl)
        #pragma unroll
        for (int ks = 0; ks < 2; ++ks) {
            f16x8 h8, r8;
            #pragma unroll
            for (int j = 0; j < 8; ++j) {
                const float v = xw[(size_t)(ks * 32 + q * 8 + j) * VQ_HW + tl * 16 + m];
                const _Float16 vh = (_Float16)v;
                h8[j] = vh;
                r8[j] = (_Float16)((v - (float)vh) * SC);
            }
            Ah[tl][ks] = h8; Ra[tl][ks] = r8;
        }

    int d1[2][4], d2[2][4];
    #pragma unroll
    for (int tl = 0; tl < 2; ++tl)
        #pragma unroll
        for (int r = 0; r < 4; ++r) { d1[tl][r] = 0x7FFFFFFF; d2[tl][r] = 0x7FFFFFFF; }

    const f32x4 zero4 = {0.f, 0.f, 0.f, 0.f};

    for (int cc = 0; cc < 16; ++cc) {
        __syncthreads();              // chunk cc staged; buf[(cc+1)&1] free
        if (cc < 15) {                // prefetch next chunk into other buffer
            const char* gsrc = (const char*)ws + (size_t)(cc + 1) * 16384 + wv * 4096 + lane * 16;
            char*       ldst = (char*)&bbuf[(cc + 1) & 1][0] + wv * 4096;
            GLOAD_LDS(gsrc, ldst);                GLOAD_LDS(gsrc + 1024, ldst + 1024);
            GLOAD_LDS(gsrc + 2048, ldst + 2048);  GLOAD_LDS(gsrc + 3072, ldst + 3072);
        }
        const f16x8* bufc = &bbuf[cc & 1][0];
        #pragma unroll
        for (int ctl = 0; ctl < 4; ++ctl) {
            const int ctg = cc * 4 + ctl;
            const f16x8 B0 = bufc[ctl * 256 +       lane];
            const f16x8 B1 = bufc[ctl * 256 +  64 + lane];
            const f16x8 R0 = bufc[ctl * 256 + 128 + lane];
            const f16x8 R1 = bufc[ctl * 256 + 192 + lane];
            const float cv = cn_lds[ctg * 16 + m];
            const f32x4 Ci = {cv, cv, cv, cv};
            f32x4 acm[2], acc[2];
            #pragma unroll
            for (int tl = 0; tl < 2; ++tl) {
                acm[tl] = __builtin_amdgcn_mfma_f32_16x16x32_f16(Ah[tl][0], B0, Ci,      0,0,0);
                acm[tl] = __builtin_amdgcn_mfma_f32_16x16x32_f16(Ah[tl][1], B1, acm[tl], 0,0,0);
                acc[tl] = __builtin_amdgcn_mfma_f32_16x16x32_f16(Ah[tl][0], R0, zero4,   0,0,0);
                acc[tl] = __builtin_amdgcn_mfma_f32_16x16x32_f16(Ah[tl][1], R1, acc[tl], 0,0,0);
                acc[tl] = __builtin_amdgcn_mfma_f32_16x16x32_f16(Ra[tl][0], B0, acc[tl], 0,0,0);
                acc[tl] = __builtin_amdgcn_mfma_f32_16x16x32_f16(Ra[tl][1], B1, acc[tl], 0,0,0);
            }
            const int code_ = ctg * 16 + m;
            #pragma unroll
            for (int tl = 0; tl < 2; ++tl)
                #pragma unroll
                for (int r = 0; r < 4; ++r) {
                    // q-units: dist*2048 = acm*2048 + acc  (SC == 2048)
                    const float qf  = fmaf(acm[tl][r], SC, acc[tl][r]);
                    const int   key = ((int)qf << 10) | code_;
                    const int   t   = (key > d1[tl][r]) ? key : d1[tl][r];
                    d2[tl][r] = (t < d2[tl][r]) ? t : d2[tl][r];
                    d1[tl][r] = (key < d1[tl][r]) ? key : d1[tl][r];
                }
        }
    }

    // ---- top-2 merge across the 16 code-columns (keys carry the code) ----
    #pragma unroll
    for (int off = 1; off < 16; off <<= 1)
        #pragma unroll
        for (int tl = 0; tl < 2; ++tl)
            #pragma unroll
            for (int r = 0; r < 4; ++r) {
                const int od1 = __shfl_xor(d1[tl][r], off, 64);
                const int od2 = __shfl_xor(d2[tl][r], off, 64);
                const int mx  = (d1[tl][r] > od1) ? d1[tl][r] : od1;
                const int mn2 = (d2[tl][r] < od2) ? d2[tl][r] : od2;
                d2[tl][r] = (mx < mn2) ? mx : mn2;
                d1[tl][r] = (d1[tl][r] < od1) ? d1[tl][r] : od1;
            }

    if (m == 0) {
        #pragma unroll
        for (int tl = 0; tl < 2; ++tl)
            #pragma unroll
            for (int r = 0; r < 4; ++r) {
                const int li = wv * 32 + tl * 16 + q * 4 + r;
                sk[li]  = d1[tl][r] & 1023;
                smg[li] = (d2[tl][r] >> 10) - (d1[tl][r] >> 10);   // gap in q-units
            }
    }
    __syncthreads();

    // ---- epilogue: indices, rescan flags, quantized scatter ----
    const int pos  = tid & 127;
    const int half = tid >> 7;        // 2 threads per position, 32 dims each
    const int bk   = sk[pos];
    if (half == 0) {
        idx_out[p0 + pos] = (float)bk;
        if (smg[pos] < EPS_Q) {
            const int slot = atomicAdd((int*)ws + WS_CNT, 1);
            ((int*)ws)[WS_LIST + slot] = p0 + pos;
        }
    }
    const float4* cr = (const float4*)(cb + (size_t)bk * VQ_D) + half * 8;
    float* ob = out + (size_t)b * (VQ_D * VQ_HW) + (size_t)(half * 32) * VQ_HW + n0 + pos;
    #pragma unroll
    for (int d4 = 0; d4 < 8; ++d4) {
        const float4 v = cr[d4];
        ob[(size_t)(d4 * 4 + 0) * VQ_HW] = v.x;
        ob[(size_t)(d4 * 4 + 1) * VQ_HW] = v.y;
        ob[(size_t)(d4 * 4 + 2) * VQ_HW] = v.z;
        ob[(size_t)(d4 * 4 + 3) * VQ_HW] = v.w;
    }
}

// ---------- rescan: exact f32 argmin for flagged positions (verified) ----------
__global__ __launch_bounds__(64)
void vq_rescan(const float* __restrict__ x,
               const float* __restrict__ cb,
               const float* __restrict__ ws,
               float* __restrict__ out,
               float* __restrict__ idx_out)
{
    __shared__ float xs[VQ_D];
    const int lane = threadIdx.x;
    const int cnt  = ((const int*)ws)[WS_CNT];
    const int* list = (const int*)ws + WS_LIST;
    const float*  cnb  = ws + WS_CBN;
    const float4* cbT4 = (const float4*)(ws + WS_CBT);

    for (int i = blockIdx.x; i < cnt; i += gridDim.x) {
        const int p = list[i];
        const int b = p >> 12, n = p & (VQ_HW - 1);
        xs[lane] = x[(size_t)b * (VQ_D * VQ_HW) + (size_t)lane * VQ_HW + n];
        __syncthreads();
        float4 xr[16];
        #pragma unroll
        for (int j = 0; j < 16; ++j) xr[j] = ((const float4*)xs)[j];

        float bd = 3.4e38f; int bk = 0;
        #pragma unroll 4
        for (int t = 0; t < 16; ++t) {
            const int code = t * 64 + lane;           // per-lane ascending
            float a0 = 0.f, a1 = 0.f, a2 = 0.f, a3 = 0.f;
            #pragma unroll
            for (int j4 = 0; j4 < 16; ++j4) {
                const float4 c = cbT4[j4 * 1024 + code];   // coalesced
                a0 = fmaf(xr[j4].x, c.x, a0); a1 = fmaf(xr[j4].y, c.y, a1);
                a2 = fmaf(xr[j4].z, c.z, a2); a3 = fmaf(xr[j4].w, c.w, a3);
            }
            const float dist = fmaf(-2.0f, (a0 + a1) + (a2 + a3), cnb[code]);
            if (dist < bd) { bd = dist; bk = code; }
        }
        #pragma unroll
        for (int off = 1; off < 64; off <<= 1) {      // min dist, tie -> min k
            const float od = __shfl_xor(bd, off, 64);
            const int   ok = __shfl_xor(bk, off, 64);
            if (od < bd || (od == bd && ok < bk)) { bd = od; bk = ok; }
        }
        out[(size_t)b * (VQ_D * VQ_HW) + (size_t)lane * VQ_HW + n] = cb[(size_t)bk * VQ_D + lane];
        if (lane == 0) idx_out[p] = (float)bk;
        __syncthreads();
    }
}

extern "C" void kernel_launch(void* const* d_in, const int* in_sizes, int n_in,
                              void* d_out, int out_size, void* d_ws, size_t ws_size,
                              hipStream_t stream) {
    const float* x  = (const float*)d_in[0];
    const float* cb = (const float*)d_in[1];
    float* out = (float*)d_out;
    float* idx = out + (size_t)VQ_NPOS * VQ_D;   // 8,388,608 floats in
    float* ws  = (float*)d_ws;                    // ~1.05 MB used

    vq_prep  <<<dim3(132),  dim3(256), 0, stream>>>(cb, ws);
    vq_main  <<<dim3(1024), dim3(256), 0, stream>>>(x, cb, ws, out, idx);
    vq_rescan<<<dim3(1024), dim3(64),  0, stream>>>(x, cb, ws, out, idx);
}